// Round 8
// baseline (236.269 us; speedup 1.0000x reference)
//
#include <hip/hip_runtime.h>

#define NSP 32
#define BB  16
#define CC  64
#define HW  (512 * 512)

#define BLOCK  256
#define CHUNK  8192
#define NCHUNK (HW / CHUNK)        // 32
#define KIT    (CHUNK / 4 / BLOCK) // 8 float4-iters per thread per pass
#define STR2   66                  // floats per private row (33 float2, odd f2-stride)

// ---------------------------------------------------------------------------
// Segmented sums + counts with ZERO intra-block synchronization.
// Bins are wave-private (each wave folds only its own 64 rows): within a wave
// lanes are lockstep and DS ops process in issue order, so the
// write -> cross-lane read -> rezero sequence needs no barrier. Waves drift
// freely, keeping the CU's VMEM queue fed through fold/flush windows.
// Partial flush is one fire-and-forget global atomic per lane per pass.
// ---------------------------------------------------------------------------
__global__ __launch_bounds__(BLOCK) void sp_accum(const float* __restrict__ feats,
                                                  const int*   __restrict__ spidx,
                                                  float*       __restrict__ sums  /*[B][C][NSP]*/,
                                                  float*       __restrict__ counts/*[B][NSP]*/)
{
    __shared__ float s_priv[BLOCK][STR2];   // 67.6 KB private bins (float2 rows)

    const int tid   = threadIdx.x;
    const int b     = blockIdx.y;
    const int pix0  = blockIdx.x * CHUNK;
    const int lane  = tid & 63;
    const int wbase = tid & ~63;            // first private row of this wave
    const int bin   = lane & 31;
    const int plane = lane >> 5;            // 0: even channel (.x), 1: odd (.y)

    float2* row = (float2*)&s_priv[tid][0];

    // --- own pixel indices -> registers ---
    uchar4 uu[KIT];
    {
        const int4* ip = (const int4*)(spidx + (size_t)b * HW + pix0);
#pragma unroll
        for (int k = 0; k < KIT; ++k) {
            int4 v = ip[k * BLOCK + tid];
            uu[k] = make_uchar4((unsigned char)(v.x & 31), (unsigned char)(v.y & 31),
                                (unsigned char)(v.z & 31), (unsigned char)(v.w & 31));
        }
    }
#pragma unroll
    for (int s = 0; s < 33; ++s) row[s] = make_float2(0.f, 0.f);

    // --- depth-1 prefetch prologue: pass 0 (channels 0,1) ---
    const float* fb = feats + (size_t)b * CC * HW + pix0;
    float4 pre[KIT][2];
#pragma unroll
    for (int k = 0; k < KIT; ++k) {
        pre[k][0] = ((const float4*)fb)[k * BLOCK + tid];
        pre[k][1] = ((const float4*)(fb + (size_t)HW))[k * BLOCK + tid];
    }

    // --- fused pixel counts in plane .x (runs under the prefetch) ---
#pragma unroll
    for (int k = 0; k < KIT; ++k) {
        row[uu[k].x].x += 1.f;
        row[uu[k].y].x += 1.f;
        row[uu[k].z].x += 1.f;
        row[uu[k].w].x += 1.f;
    }
    {
        // wave-fold: plane-1 lanes read the untouched .y plane (= 0) and add 0
        float p0 = 0.f, p1 = 0.f;
#pragma unroll
        for (int r = 0; r < 64; r += 2) {
            p0 += s_priv[wbase + r][2 * bin + plane];
            p1 += s_priv[wbase + r + 1][2 * bin + plane];
        }
        atomicAdd(&counts[b * NSP + bin], p0 + p1);   // fire-and-forget
    }
#pragma unroll
    for (int s = 0; s < 33; ++s) row[s] = make_float2(0.f, 0.f);

    // --- main channel-pair passes: NO barriers anywhere ---
    for (int p = 0; p < CC / 2; ++p) {
        const int ch0 = 2 * p;

        // accumulate this pass from prefetched registers (plain serial RMW)
#pragma unroll
        for (int k = 0; k < KIT; ++k) {
            const uchar4 u = uu[k];
            const float4 a = pre[k][0], c = pre[k][1];
            float2 t;
            t = row[u.x]; t.x += a.x; t.y += c.x; row[u.x] = t;
            t = row[u.y]; t.x += a.y; t.y += c.y; row[u.y] = t;
            t = row[u.z]; t.x += a.z; t.y += c.z; row[u.z] = t;
            t = row[u.w]; t.x += a.w; t.y += c.w; row[u.w] = t;
        }
        // refill for pass p+1 — loads in flight across the fold
        if (p + 1 < CC / 2) {
            const float* g0 = fb + (size_t)(ch0 + 2) * HW;
#pragma unroll
            for (int k = 0; k < KIT; ++k) {
                pre[k][0] = ((const float4*)g0)[k * BLOCK + tid];
                pre[k][1] = ((const float4*)(g0 + (size_t)HW))[k * BLOCK + tid];
            }
        }
        // wave-fold own 64 rows: lane -> (bin, plane); 2-way broadcast reads,
        // two dependence chains for ILP. In-order DS per wave makes the
        // preceding writes visible; compiler waits on the read data itself.
        float p0 = 0.f, p1 = 0.f;
#pragma unroll
        for (int r = 0; r < 64; r += 2) {
            p0 += s_priv[wbase + r][2 * bin + plane];
            p1 += s_priv[wbase + r + 1][2 * bin + plane];
        }
        atomicAdd(&sums[((size_t)b * CC + ch0 + plane) * NSP + bin], p0 + p1);
        // rezero own row; issued after all fold reads (in-order DS per wave)
#pragma unroll
        for (int s = 0; s < 33; ++s) row[s] = make_float2(0.f, 0.f);
    }
}

// ---------------------------------------------------------------------------
// Mean + pairwise similarity. One block per batch.
// out layout: sp [B][NSP][C] at 0, sim [B][NSP][NSP] at B*NSP*C
// ---------------------------------------------------------------------------
__global__ __launch_bounds__(256) void sp_finalize(const float* __restrict__ sums,
                                                   const float* __restrict__ counts,
                                                   float*       __restrict__ out)
{
    __shared__ float s_sp[NSP][CC + 1];
    const int b   = blockIdx.x;
    const int tid = threadIdx.x;

    for (int i = tid; i < NSP * CC; i += 256) {
        int sp = i >> 6, c = i & 63;
        float cnt = counts[b * NSP + sp];
        float s   = sums[((size_t)b * CC + c) * NSP + sp];
        float v   = (cnt > 0.0f) ? (s / cnt) : 0.0f;
        s_sp[sp][c] = v;
        out[(size_t)b * NSP * CC + (size_t)sp * CC + c] = v;
    }
    __syncthreads();

    for (int p = tid; p < NSP * NSP; p += 256) {
        int i = p >> 5, j = p & 31;
        float acc = 0.0f;
#pragma unroll
        for (int c = 0; c < CC; ++c) {
            float d = s_sp[i][c] - s_sp[j][c];
            acc = fmaf(d, d, acc);
        }
        out[(size_t)BB * NSP * CC + (size_t)b * NSP * NSP + p] = 1.0f - 0.5f * acc;
    }
}

// ---------------------------------------------------------------------------
extern "C" void kernel_launch(void* const* d_in, const int* in_sizes, int n_in,
                              void* d_out, int out_size, void* d_ws, size_t ws_size,
                              hipStream_t stream)
{
    const float* feats = (const float*)d_in[0];
    const int*   spidx = (const int*)d_in[1];
    float*       out   = (float*)d_out;

    float* sums   = (float*)d_ws;                     // B*C*NSP = 32768 floats
    float* counts = sums + (size_t)BB * CC * NSP;     // B*NSP   = 512 floats

    hipMemsetAsync(d_ws, 0, ((size_t)BB * CC * NSP + (size_t)BB * NSP) * sizeof(float), stream);

    dim3 g1(NCHUNK, BB);
    sp_accum<<<g1, BLOCK, 0, stream>>>(feats, spidx, sums, counts);

    sp_finalize<<<BB, 256, 0, stream>>>(sums, counts, out);
}

// Round 9
// 213.164 us; speedup vs baseline: 1.1084x; 1.1084x over previous
//
#include <hip/hip_runtime.h>

#define NSP 32
#define BB  16
#define CC  64
#define HW  (512 * 512)

#define BLOCK  256
#define CHUNK  8192
#define NCHUNK (HW / CHUNK)      // 32
#define KIT    (CHUNK / 4 / BLOCK)  // 8 float4-iters per thread per pass

// Barrier that does NOT drain vmcnt: all cross-thread deps here are LDS-only,
// so prefetched global loads may stay in flight across the fold phase.
#define BAR() asm volatile("s_waitcnt lgkmcnt(0)\n\ts_barrier" ::: "memory")

// ---------------------------------------------------------------------------
// Segmented sums + counts. Per-thread privatized LDS bins (no atomics in the
// hot loop). Each block: one 8192-pixel chunk, sweeps 64 channels in pairs.
// Next pass's feature data is fully prefetched into registers before the
// fold barrier, so HBM never idles during fold/rezero.
// Measured best: 213.2 us total (round 3). Ledger of falsified variants:
// ds_atomics 7x slower; dup-merge null; depth-2 prefetch -3%; 4 small
// blocks/CU -3%; zero-barrier wave-private fold -10%.
// ---------------------------------------------------------------------------
__global__ __launch_bounds__(BLOCK) void sp_accum(const float* __restrict__ feats,
                                                  const int*   __restrict__ spidx,
                                                  float*       __restrict__ sums  /*[B][C][NSP]*/,
                                                  float*       __restrict__ counts/*[B][NSP]*/)
{
    __shared__ uchar4 s_idx[CHUNK / 4];               // 8 KB
    __shared__ float2 s_priv[BLOCK][NSP + 1];         // 66 KB, pad -> bank spread
    __shared__ float2 s_part[8][NSP];                 // 2 KB

    const int tid  = threadIdx.x;
    const int b    = blockIdx.y;
    const int pix0 = blockIdx.x * CHUNK;
    const int bin  = tid & 31;
    const int grp  = tid >> 5;

    // stage indices as bytes (read once from HBM, reused for all passes)
    const int4* ip = (const int4*)(spidx + (size_t)b * HW + pix0);
#pragma unroll
    for (int n = 0; n < (CHUNK / 4) / BLOCK; ++n) {
        const int i = n * BLOCK + tid;
        int4 v = ip[i];
        s_idx[i] = make_uchar4((unsigned char)(v.x & 31), (unsigned char)(v.y & 31),
                               (unsigned char)(v.z & 31), (unsigned char)(v.w & 31));
    }
#pragma unroll
    for (int sp = 0; sp < NSP; ++sp) s_priv[tid][sp] = make_float2(0.f, 0.f);

    // prologue: prefetch pass 0 (channels 0,1) fully — in flight during count phase
    const float* fb = feats + (size_t)b * CC * HW + pix0;
    float4 pre[KIT][2];
#pragma unroll
    for (int k = 0; k < KIT; ++k) {
        pre[k][0] = ((const float4*)fb)[k * BLOCK + tid];
        pre[k][1] = ((const float4*)(fb + (size_t)HW))[k * BLOCK + tid];
    }

    BAR();

    // ---- fused pixel counts (uses .x plane of the private bins) ----
    {
        float* rowf = (float*)&s_priv[tid][0];
#pragma unroll
        for (int k = 0; k < KIT; ++k) {
            uchar4 u = s_idx[k * BLOCK + tid];
            rowf[u.x * 2] += 1.f;
            rowf[u.y * 2] += 1.f;
            rowf[u.z * 2] += 1.f;
            rowf[u.w * 2] += 1.f;
        }
    }
    BAR();
    {
        float a = 0.f;
#pragma unroll
        for (int m = 0; m < BLOCK / 8; ++m) a += s_priv[grp + m * 8][bin].x;
        s_part[grp][bin].x = a;
    }
    BAR();
    if (tid < NSP) {
        float r = 0.f;
#pragma unroll
        for (int g = 0; g < 8; ++g) r += s_part[g][tid].x;
        atomicAdd(&counts[b * NSP + tid], r);
    }
#pragma unroll
    for (int sp = 0; sp < NSP; ++sp) s_priv[tid][sp] = make_float2(0.f, 0.f);
    BAR();

    // ---- main channel-pair passes ----
    float2* row = s_priv[tid];
    for (int cp = 0; cp < CC / 2; ++cp) {
        // A: accumulate this pass from prefetched registers
#pragma unroll
        for (int k = 0; k < KIT; ++k) {
            uchar4 u = s_idx[k * BLOCK + tid];
            float4 a = pre[k][0], c = pre[k][1];
            float2 t;
            t = row[u.x]; t.x += a.x; t.y += c.x; row[u.x] = t;
            t = row[u.y]; t.x += a.y; t.y += c.y; row[u.y] = t;
            t = row[u.z]; t.x += a.z; t.y += c.z; row[u.z] = t;
            t = row[u.w]; t.x += a.w; t.y += c.w; row[u.w] = t;
        }
        // B: issue next pass's loads — they stay in flight across the fold
        if (cp + 1 < CC / 2) {
            const float* g0 = fb + (size_t)(2 * cp + 2) * HW;
#pragma unroll
            for (int k = 0; k < KIT; ++k) {
                pre[k][0] = ((const float4*)g0)[k * BLOCK + tid];
                pre[k][1] = ((const float4*)(g0 + (size_t)HW))[k * BLOCK + tid];
            }
        }
        BAR();
        // fold 256 private copies: 8 threads per bin, 32 copies each
        {
            float2 acc = make_float2(0.f, 0.f);
#pragma unroll
            for (int m = 0; m < BLOCK / 8; ++m) {
                float2 v = s_priv[grp + m * 8][bin];
                acc.x += v.x; acc.y += v.y;
            }
            s_part[grp][bin] = acc;
        }
        BAR();
        if (cp + 1 < CC / 2) {
#pragma unroll
            for (int sp = 0; sp < NSP; ++sp) row[sp] = make_float2(0.f, 0.f);
        }
        if (tid < NSP) {
            float2 r = s_part[0][tid];
#pragma unroll
            for (int g = 1; g < 8; ++g) { r.x += s_part[g][tid].x; r.y += s_part[g][tid].y; }
            atomicAdd(&sums[((size_t)b * CC + 2 * cp)     * NSP + tid], r.x);
            atomicAdd(&sums[((size_t)b * CC + 2 * cp + 1) * NSP + tid], r.y);
        }
        BAR();   // s_part / s_priv safe before next pass
    }
}

// ---------------------------------------------------------------------------
// Mean + pairwise similarity. One block per batch.
// out layout: sp [B][NSP][C] at 0, sim [B][NSP][NSP] at B*NSP*C
// ---------------------------------------------------------------------------
__global__ __launch_bounds__(BLOCK) void sp_finalize(const float* __restrict__ sums,
                                                     const float* __restrict__ counts,
                                                     float*       __restrict__ out)
{
    __shared__ float s_sp[NSP][CC + 1];
    const int b   = blockIdx.x;
    const int tid = threadIdx.x;

    for (int i = tid; i < NSP * CC; i += BLOCK) {
        int sp = i >> 6, c = i & 63;
        float cnt = counts[b * NSP + sp];
        float s   = sums[((size_t)b * CC + c) * NSP + sp];
        float v   = (cnt > 0.0f) ? (s / cnt) : 0.0f;
        s_sp[sp][c] = v;
        out[(size_t)b * NSP * CC + (size_t)sp * CC + c] = v;
    }
    __syncthreads();

    for (int p = tid; p < NSP * NSP; p += BLOCK) {
        int i = p >> 5, j = p & 31;
        float acc = 0.0f;
#pragma unroll
        for (int c = 0; c < CC; ++c) {
            float d = s_sp[i][c] - s_sp[j][c];
            acc = fmaf(d, d, acc);
        }
        out[(size_t)BB * NSP * CC + (size_t)b * NSP * NSP + p] = 1.0f - 0.5f * acc;
    }
}

// ---------------------------------------------------------------------------
extern "C" void kernel_launch(void* const* d_in, const int* in_sizes, int n_in,
                              void* d_out, int out_size, void* d_ws, size_t ws_size,
                              hipStream_t stream)
{
    const float* feats = (const float*)d_in[0];
    const int*   spidx = (const int*)d_in[1];
    float*       out   = (float*)d_out;

    float* sums   = (float*)d_ws;                     // B*C*NSP = 32768 floats
    float* counts = sums + (size_t)BB * CC * NSP;     // B*NSP   = 512 floats

    hipMemsetAsync(d_ws, 0, ((size_t)BB * CC * NSP + (size_t)BB * NSP) * sizeof(float), stream);

    dim3 g1(NCHUNK, BB);
    sp_accum<<<g1, BLOCK, 0, stream>>>(feats, spidx, sums, counts);

    sp_finalize<<<BB, BLOCK, 0, stream>>>(sums, counts, out);
}